// Round 19
// baseline (163.542 us; speedup 1.0000x reference)
//
#include <hip/hip_runtime.h>

// WL-conv factorized:  out[b,c,n,k] = Y0 + e1[c,k]*Y1 + e2[c,k]*Y2 + e3[c,k]*Y3
// with Ym = M^m labels and e_m the elementary symmetric polynomials of
// kernels[c,0..2,k] (per-step operators I + k_t∘M commute).
//
// 4 stream-ordered kernels:
//   pack: STANDALONE, 2048 blocks (one per 16-row x 2048-col HALF-tile,
//         128 KB read each). 8 blocks/CU queued, 4 resident -> a finishing
//         block's barrier/dump stall is covered by a successor's streaming
//         (R16's fused K1 had 0 oversubscription: stalls were exposed).
//         Depth-8 load pipeline; 4 KB coalesced tile dump; prep fused.
//   s1/s2/s3: the R16-proven 32-row spmm (512 blocks, 2/CU): two 16-row
//         tiles share each B-fragment load; masks+B in depth-4 rolling
//         register pipelines; s3 fuses combine + vectorized f4 epilogue.
// bits layout: bits[((b*256+rt)*64 + w)*16 + r]  (block-coalesced tiles)
// Y chained in ypos-permuted MFMA-B-fragment layout (coalesced 1KB B loads).
//
// d_out (8 MB): final output only.
// d_ws: bits 8MB | ysw0 | ysw1 | ysw2 (0.5 MB each, swizzled bf16).

#define BB 4
#define NN 4096
#define KK 16
#define CC 8
#define TT 3
#define WPR (NN / 64)
#define YSWZ (KK * NN)   // u16 elements per batch in swizzled Y (65536)

typedef unsigned long long u64;
typedef unsigned int u32;
typedef unsigned short u16;
typedef __attribute__((ext_vector_type(8))) short s16x8;
typedef __attribute__((ext_vector_type(4))) float f32x4v;

__device__ __forceinline__ u32 bf16_rne(float f) {
    u32 u = __float_as_uint(f);
    return (u + 0x7FFFu + ((u >> 16) & 1u)) >> 16;
}
__device__ __forceinline__ float bf16_f32(u32 h) {
    return __uint_as_float(h << 16);
}
__device__ __forceinline__ long ypos(int f, int s) {
    return ((long)(s >> 8) << 12) + (s & 3) * 1024 + ((s >> 7) & 1) * 512 +
           f * 32 + ((s >> 5) & 3) * 8 + ((s >> 2) & 7);
}

// byte (8 mask bits) -> 8 bf16 {0,1} packed in s16x8 (elem i = bit i)
__device__ __forceinline__ s16x8 expand8(u32 byt) {
    u32 n0 = byt & 0xFu, n1 = (byt >> 4) & 0xFu;
    u32 t0 = (n0 * 0x204081u) & 0x01010101u;
    u32 t1 = (n1 * 0x204081u) & 0x01010101u;
    u32 m0 = (t0 << 7) - t0;
    u32 m1 = (t1 << 7) - t1;
    union { u32 w[4]; s16x8 v; } u;
    u.w[0] = __builtin_amdgcn_perm(0u, m0, 0x0C010C00u) << 7;
    u.w[1] = __builtin_amdgcn_perm(0u, m0, 0x0C030C02u) << 7;
    u.w[2] = __builtin_amdgcn_perm(0u, m1, 0x0C010C00u) << 7;
    u.w[3] = __builtin_amdgcn_perm(0u, m1, 0x0C030C02u) << 7;
    return u.v;
}

// ---------------------------------------------------------------- pack ------
// grid = BB * 256 rt * 2 halves = 2048 blocks of 256 threads (4 waves).
// Block (b, rt, h): rows [16rt,16rt+16) x cols [2048h, 2048h+2048).
// Wave ss: i in [0,32): row = i&15, w4l = ss*2 + (i>>4); depth-8 pipeline.
// Ballot word mapping identical to R16 (wql = w4l*4 + component).
// First 256 blocks also run prep (labels -> swizzled bf16 Y0).
__global__ __launch_bounds__(256, 4)
void pack_kernel(const int* __restrict__ lig, u64* __restrict__ bits,
                 const float* __restrict__ labels, u16* __restrict__ ysw0)
{
    __shared__ u64 bl[32][16];                   // [w_local][row] 4 KB
    const int bid = blockIdx.x;
    const int h   = bid & 1;
    const int rt  = (bid >> 1) & 255;
    const int b   = bid >> 9;
    const int tid = threadIdx.x;
    const int lane = tid & 63, ss = tid >> 6;
    const int row0 = rt * 16;

    // prep fused (first 256 blocks, one task per thread)
    int gid = bid * 256 + tid;
    if (gid < BB * KK * (NN / 4)) {              // 65536 tasks
        int s4 = (gid & (NN / 4 - 1)) * 4;
        int f  = (gid >> 10) & (KK - 1);
        int pb = gid >> 14;
        long base = (long)pb * YSWZ + ypos(f, s4);
        const float* lp = labels + ((long)pb * NN + s4) * KK + f;
#pragma unroll
        for (int j = 0; j < 4; ++j)
            ysw0[base + j * 1024] = (u16)bf16_rne(lp[j * KK]);
    }

    const int* lrow = lig + ((long)b * NN + row0) * NN + h * 2048;
    auto laddr = [&](int i) {
        int row = i & 15, w4l = ss * 2 + (i >> 4);
        return (const int4*)(lrow + (long)row * NN + w4l * 256 + lane * 4);
    };
    int4 v[8];
#pragma unroll
    for (int i = 0; i < 8; ++i) v[i] = *laddr(i);
#pragma unroll 4
    for (int i = 0; i < 32; ++i) {
        const int slot = i & 7;
        int4 cur = v[slot];
        if (i + 8 < 32) v[slot] = *laddr(i + 8);
        u64 m0 = __ballot(cur.x >= 1);
        u64 m1 = __ballot(cur.y >= 1);
        u64 m2 = __ballot(cur.z >= 1);
        u64 m3 = __ballot(cur.w >= 1);
        if (lane == 0) {
            const int row = i & 15;
            const int wql = (ss * 2 + (i >> 4)) * 4;     // local word quad
            bl[wql + 0][row] = m0; bl[wql + 1][row] = m1;
            bl[wql + 2][row] = m2; bl[wql + 3][row] = m3;
        }
    }
    __syncthreads();
    // coalesced 4 KB half-tile dump: words [32h, 32h+32)
    uint4* dst = (uint4*)(bits + (long)(b * 256 + rt) * 1024 + h * 512);
    dst[tid] = ((const uint4*)&bl[0][0])[tid];
}

// ------------------------------------------------- 32-row spmm [R16] --------
// grid = BB*(NN/32) = 512 blocks of 256 threads, 2 blocks/CU (bounds 256,2).
// Two 16-row tiles (rt0, rt1) share every B-fragment load.
template<bool LAST>
__global__ __launch_bounds__(256, 2)
void spmm2_k(const u64* __restrict__ bits, const u16* __restrict__ yin,
             u16* __restrict__ yout, const u16* __restrict__ ysw1,
             const u16* __restrict__ ysw2, const float* __restrict__ labels,
             const float* __restrict__ ker, float* __restrict__ out)
{
    __shared__ float red[2][3][4][64];                    // 6 KB
    __shared__ float t1[32][16], t2[32][16], t3[32][16];  // 6 KB (LAST)
    const int bid = blockIdx.x;
    const int rtp = bid & (NN / 32 - 1);
    const int b   = bid >> 7;
    const int tid = threadIdx.x;
    const int lane = tid & 63, ss = tid >> 6;
    const int n16 = lane & 15, g = lane >> 4;
    const int row0 = rtp * 32;
    const int rt0 = 2 * rtp, rt1 = 2 * rtp + 1;

    const u64* bb0 = bits + ((long)(b * (NN / 16) + rt0) * 64 + ss * 16) * 16 + n16;
    const u64* bb1 = bits + ((long)(b * (NN / 16) + rt1) * 64 + ss * 16) * 16 + n16;
    const u16* yb  = yin + (long)b * YSWZ + (ss * 16) * 1024 + n16 * 32 + g * 8;

    s16x8 p0[4], p1[4]; u64 m0[4], m1[4];
#pragma unroll
    for (int i = 0; i < 4; ++i) {
        p0[i] = *(const s16x8*)(yb + i * 1024);
        p1[i] = *(const s16x8*)(yb + i * 1024 + 512);
        m0[i] = bb0[i * 16];
        m1[i] = bb1[i * 16];
    }

    f32x4v accA0 = {0.f,0.f,0.f,0.f}, accB0 = {0.f,0.f,0.f,0.f};
    f32x4v accA1 = {0.f,0.f,0.f,0.f}, accB1 = {0.f,0.f,0.f,0.f};
#pragma unroll
    for (int wi = 0; wi < 16; ++wi) {
        const int slot = wi & 3;
        s16x8 b0 = p0[slot], b1 = p1[slot];
        u64 h0 = m0[slot], h1 = m1[slot];
        if (wi + 4 < 16) {
            p0[slot] = *(const s16x8*)(yb + (wi + 4) * 1024);
            p1[slot] = *(const s16x8*)(yb + (wi + 4) * 1024 + 512);
            m0[slot] = bb0[(wi + 4) * 16];
            m1[slot] = bb1[(wi + 4) * 16];
        }
        u64 ha = h0 >> (g * 8), hb = h1 >> (g * 8);
        accA0 = __builtin_amdgcn_mfma_f32_16x16x32_bf16(expand8((u32)ha & 0xFFu), b0, accA0, 0, 0, 0);
        accB0 = __builtin_amdgcn_mfma_f32_16x16x32_bf16(expand8(((u32)(ha >> 32)) & 0xFFu), b1, accB0, 0, 0, 0);
        accA1 = __builtin_amdgcn_mfma_f32_16x16x32_bf16(expand8((u32)hb & 0xFFu), b0, accA1, 0, 0, 0);
        accB1 = __builtin_amdgcn_mfma_f32_16x16x32_bf16(expand8(((u32)(hb >> 32)) & 0xFFu), b1, accB1, 0, 0, 0);
    }

    f32x4v acc0, acc1;
#pragma unroll
    for (int r = 0; r < 4; ++r) { acc0[r] = accA0[r] + accB0[r];
                                  acc1[r] = accA1[r] + accB1[r]; }

    const int s0a = row0 + 4 * g;
    const int s0b = row0 + 16 + 4 * g;
    const long yba = (long)b * YSWZ + ypos(n16, s0a);
    const long ybb = (long)b * YSWZ + ypos(n16, s0b);
    float y1a[4], y2a[4], y1b[4], y2b[4];
    if (LAST && ss == 0) {
#pragma unroll
        for (int r = 0; r < 4; ++r) {
            y1a[r] = bf16_f32(ysw1[yba + r * 1024]);
            y2a[r] = bf16_f32(ysw2[yba + r * 1024]);
            y1b[r] = bf16_f32(ysw1[ybb + r * 1024]);
            y2b[r] = bf16_f32(ysw2[ybb + r * 1024]);
        }
    }

    if (ss != 0) {
#pragma unroll
        for (int r = 0; r < 4; ++r) {
            red[0][ss - 1][r][lane] = acc0[r];
            red[1][ss - 1][r][lane] = acc1[r];
        }
    }
    __syncthreads();
    if (ss == 0) {
#pragma unroll
        for (int r = 0; r < 4; ++r) {
            acc0[r] += red[0][0][r][lane] + red[0][1][r][lane] + red[0][2][r][lane];
            acc1[r] += red[1][0][r][lane] + red[1][1][r][lane] + red[1][2][r][lane];
        }
        if (!LAST) {
#pragma unroll
            for (int r = 0; r < 4; ++r) {
                yout[yba + r * 1024] = (u16)bf16_rne(acc0[r]);
                yout[ybb + r * 1024] = (u16)bf16_rne(acc1[r]);
            }
        } else {
#pragma unroll
            for (int r = 0; r < 4; ++r) {
                t1[4 * g + r][n16]      = y1a[r];
                t2[4 * g + r][n16]      = y2a[r];
                t3[4 * g + r][n16]      = acc0[r];
                t1[16 + 4 * g + r][n16] = y1b[r];
                t2[16 + 4 * g + r][n16] = y2b[r];
                t3[16 + 4 * g + r][n16] = acc1[r];
            }
        }
    }

    if (LAST) {
        __syncthreads();
#pragma unroll
        for (int j = 0; j < 4; ++j) {
            int fi = tid + j * 256;
            int c = fi >> 7, row = (fi >> 2) & 31, k4 = fi & 3;
            const float4* kf = (const float4*)ker;
            float4 a = kf[(c * TT + 0) * 4 + k4];
            float4 d = kf[(c * TT + 1) * 4 + k4];
            float4 e = kf[(c * TT + 2) * 4 + k4];
            float4 e1, e2, e3;
            e1.x = a.x + d.x + e.x;               e1.y = a.y + d.y + e.y;
            e1.z = a.z + d.z + e.z;               e1.w = a.w + d.w + e.w;
            e2.x = a.x*d.x + a.x*e.x + d.x*e.x;   e2.y = a.y*d.y + a.y*e.y + d.y*e.y;
            e2.z = a.z*d.z + a.z*e.z + d.z*e.z;   e2.w = a.w*d.w + a.w*e.w + d.w*e.w;
            e3.x = a.x * d.x * e.x;               e3.y = a.y * d.y * e.y;
            e3.z = a.z * d.z * e.z;               e3.w = a.w * d.w * e.w;
            float4 y0 = *(const float4*)(labels + ((long)b * NN + row0 + row) * KK + k4 * 4);
            float4 v1 = *(const float4*)&t1[row][k4 * 4];
            float4 v2 = *(const float4*)&t2[row][k4 * 4];
            float4 v3 = *(const float4*)&t3[row][k4 * 4];
            float4 r;
            r.x = y0.x + e1.x * v1.x + e2.x * v2.x + e3.x * v3.x;
            r.y = y0.y + e1.y * v1.y + e2.y * v2.y + e3.y * v3.y;
            r.z = y0.z + e1.z * v1.z + e2.z * v2.z + e3.z * v3.z;
            r.w = y0.w + e1.w * v1.w + e2.w * v2.w + e3.w * v3.w;
            *(float4*)(out + (((long)b * CC + c) * NN + row0 + row) * KK + k4 * 4) = r;
        }
    }
}

// --------------------------------------------------------------- launch -----
extern "C" void kernel_launch(void* const* d_in, const int* in_sizes, int n_in,
                              void* d_out, int out_size, void* d_ws, size_t ws_size,
                              hipStream_t stream) {
    const float* labels = (const float*)d_in[0];   // [B,N,K] f32
    const int*   lig    = (const int*)d_in[1];     // [B,N,N] i32
    const float* ker    = (const float*)d_in[2];   // [C,T,K] f32
    float* out = (float*)d_out;

    u64* bits = (u64*)d_ws;                        // 8 MB
    u16* ysw0 = (u16*)((char*)d_ws + (long)BB * WPR * NN * 8);
    u16* ysw1 = ysw0 + (long)BB * YSWZ;
    u16* ysw2 = ysw1 + (long)BB * YSWZ;

    hipLaunchKernelGGL(pack_kernel, dim3(BB * 256 * 2), dim3(256), 0, stream,
                       lig, bits, labels, ysw0);

    dim3 sgrid(BB * (NN / 32));                    // 512 blocks
    hipLaunchKernelGGL((spmm2_k<false>), sgrid, dim3(256), 0, stream,
                       bits, ysw0, ysw1, (const u16*)nullptr,
                       (const u16*)nullptr, (const float*)nullptr,
                       (const float*)nullptr, (float*)nullptr);
    hipLaunchKernelGGL((spmm2_k<false>), sgrid, dim3(256), 0, stream,
                       bits, ysw1, ysw2, (const u16*)nullptr,
                       (const u16*)nullptr, (const float*)nullptr,
                       (const float*)nullptr, (float*)nullptr);
    hipLaunchKernelGGL((spmm2_k<true>),  sgrid, dim3(256), 0, stream,
                       bits, ysw2, (u16*)nullptr, ysw1, ysw2,
                       labels, ker, out);
}

// Round 20
// 75.581 us; speedup vs baseline: 2.1638x; 2.1638x over previous
//
#include <hip/hip_runtime.h>

// WL-conv factorized:  out[b,c,n,k] = Y0 + e1[c,k]*Y1 + e2[c,k]*Y2 + e3[c,k]*Y3
// with Ym = M^m labels and e_m the elementary symmetric polynomials of
// kernels[c,0..2,k] (per-step operators I + k_t∘M commute).
//
// 4 stream-ordered kernels:
//   pack: STANDALONE, 2048 blocks (one per 16-row x 2048-col HALF-tile).
//         R19 BUG FIX (rule #20): the pipeline loop is now `#pragma unroll 8`
//         so slot = i&7 is compile-time static and v[8] stays in REGISTERS.
//         (R19's unroll-4 made slot dynamic -> v[] spilled to scratch:
//         VGPR=24, 268 MB phantom writes, 3.5 TB/s, 152 us.)
//         8 blocks/CU queued; 4 KB coalesced tile dump; prep fused.
//   s1/s2/s3: the R16-proven 32-row spmm (512 blocks, 2/CU): two 16-row
//         tiles share each B-fragment load; masks+B in depth-4 rolling
//         register pipelines; s3 fuses combine + vectorized f4 epilogue.
// bits layout: bits[((b*256+rt)*64 + w)*16 + r]  (block-coalesced tiles)
// Y chained in ypos-permuted MFMA-B-fragment layout (coalesced 1KB B loads).
//
// d_out (8 MB): final output only.
// d_ws: bits 8MB | ysw0 | ysw1 | ysw2 (0.5 MB each, swizzled bf16).

#define BB 4
#define NN 4096
#define KK 16
#define CC 8
#define TT 3
#define WPR (NN / 64)
#define YSWZ (KK * NN)   // u16 elements per batch in swizzled Y (65536)

typedef unsigned long long u64;
typedef unsigned int u32;
typedef unsigned short u16;
typedef __attribute__((ext_vector_type(8))) short s16x8;
typedef __attribute__((ext_vector_type(4))) float f32x4v;

__device__ __forceinline__ u32 bf16_rne(float f) {
    u32 u = __float_as_uint(f);
    return (u + 0x7FFFu + ((u >> 16) & 1u)) >> 16;
}
__device__ __forceinline__ float bf16_f32(u32 h) {
    return __uint_as_float(h << 16);
}
__device__ __forceinline__ long ypos(int f, int s) {
    return ((long)(s >> 8) << 12) + (s & 3) * 1024 + ((s >> 7) & 1) * 512 +
           f * 32 + ((s >> 5) & 3) * 8 + ((s >> 2) & 7);
}

// byte (8 mask bits) -> 8 bf16 {0,1} packed in s16x8 (elem i = bit i)
__device__ __forceinline__ s16x8 expand8(u32 byt) {
    u32 n0 = byt & 0xFu, n1 = (byt >> 4) & 0xFu;
    u32 t0 = (n0 * 0x204081u) & 0x01010101u;
    u32 t1 = (n1 * 0x204081u) & 0x01010101u;
    u32 m0 = (t0 << 7) - t0;
    u32 m1 = (t1 << 7) - t1;
    union { u32 w[4]; s16x8 v; } u;
    u.w[0] = __builtin_amdgcn_perm(0u, m0, 0x0C010C00u) << 7;
    u.w[1] = __builtin_amdgcn_perm(0u, m0, 0x0C030C02u) << 7;
    u.w[2] = __builtin_amdgcn_perm(0u, m1, 0x0C010C00u) << 7;
    u.w[3] = __builtin_amdgcn_perm(0u, m1, 0x0C030C02u) << 7;
    return u.v;
}

// ---------------------------------------------------------------- pack ------
// grid = BB * 256 rt * 2 halves = 2048 blocks of 256 threads (4 waves).
// Block (b, rt, h): rows [16rt,16rt+16) x cols [2048h, 2048h+2048).
// Wave ss: i in [0,32): row = i&15, w4l = ss*2 + (i>>4); depth-8 pipeline,
// FULLY STATIC slots (unroll 8). Ballot word mapping identical to R16.
// First 256 blocks also run prep (labels -> swizzled bf16 Y0).
__global__ __launch_bounds__(256, 4)
void pack_kernel(const int* __restrict__ lig, u64* __restrict__ bits,
                 const float* __restrict__ labels, u16* __restrict__ ysw0)
{
    __shared__ u64 bl[32][16];                   // [w_local][row] 4 KB
    const int bid = blockIdx.x;
    const int h   = bid & 1;
    const int rt  = (bid >> 1) & 255;
    const int b   = bid >> 9;
    const int tid = threadIdx.x;
    const int lane = tid & 63, ss = tid >> 6;
    const int row0 = rt * 16;

    // prep fused (first 256 blocks, one task per thread)
    int gid = bid * 256 + tid;
    if (gid < BB * KK * (NN / 4)) {              // 65536 tasks
        int s4 = (gid & (NN / 4 - 1)) * 4;
        int f  = (gid >> 10) & (KK - 1);
        int pb = gid >> 14;
        long base = (long)pb * YSWZ + ypos(f, s4);
        const float* lp = labels + ((long)pb * NN + s4) * KK + f;
#pragma unroll
        for (int j = 0; j < 4; ++j)
            ysw0[base + j * 1024] = (u16)bf16_rne(lp[j * KK]);
    }

    const int* lrow = lig + ((long)b * NN + row0) * NN + h * 2048;
    auto laddr = [&](int i) {
        int row = i & 15, w4l = ss * 2 + (i >> 4);
        return (const int4*)(lrow + (long)row * NN + w4l * 256 + lane * 4);
    };
    int4 v[8];
#pragma unroll
    for (int i = 0; i < 8; ++i) v[i] = *laddr(i);
#pragma unroll 8
    for (int i = 0; i < 32; ++i) {
        const int slot = i & 7;                  // STATIC under unroll 8
        int4 cur = v[slot];
        if (i + 8 < 32) v[slot] = *laddr(i + 8);
        u64 m0 = __ballot(cur.x >= 1);
        u64 m1 = __ballot(cur.y >= 1);
        u64 m2 = __ballot(cur.z >= 1);
        u64 m3 = __ballot(cur.w >= 1);
        if (lane == 0) {
            const int row = i & 15;
            const int wql = (ss * 2 + (i >> 4)) * 4;     // local word quad
            bl[wql + 0][row] = m0; bl[wql + 1][row] = m1;
            bl[wql + 2][row] = m2; bl[wql + 3][row] = m3;
        }
    }
    __syncthreads();
    // coalesced 4 KB half-tile dump: words [32h, 32h+32)
    uint4* dst = (uint4*)(bits + (long)(b * 256 + rt) * 1024 + h * 512);
    dst[tid] = ((const uint4*)&bl[0][0])[tid];
}

// ------------------------------------------------- 32-row spmm [R16] --------
// grid = BB*(NN/32) = 512 blocks of 256 threads, 2 blocks/CU (bounds 256,2).
// Two 16-row tiles (rt0, rt1) share every B-fragment load.
template<bool LAST>
__global__ __launch_bounds__(256, 2)
void spmm2_k(const u64* __restrict__ bits, const u16* __restrict__ yin,
             u16* __restrict__ yout, const u16* __restrict__ ysw1,
             const u16* __restrict__ ysw2, const float* __restrict__ labels,
             const float* __restrict__ ker, float* __restrict__ out)
{
    __shared__ float red[2][3][4][64];                    // 6 KB
    __shared__ float t1[32][16], t2[32][16], t3[32][16];  // 6 KB (LAST)
    const int bid = blockIdx.x;
    const int rtp = bid & (NN / 32 - 1);
    const int b   = bid >> 7;
    const int tid = threadIdx.x;
    const int lane = tid & 63, ss = tid >> 6;
    const int n16 = lane & 15, g = lane >> 4;
    const int row0 = rtp * 32;
    const int rt0 = 2 * rtp, rt1 = 2 * rtp + 1;

    const u64* bb0 = bits + ((long)(b * (NN / 16) + rt0) * 64 + ss * 16) * 16 + n16;
    const u64* bb1 = bits + ((long)(b * (NN / 16) + rt1) * 64 + ss * 16) * 16 + n16;
    const u16* yb  = yin + (long)b * YSWZ + (ss * 16) * 1024 + n16 * 32 + g * 8;

    s16x8 p0[4], p1[4]; u64 m0[4], m1[4];
#pragma unroll
    for (int i = 0; i < 4; ++i) {
        p0[i] = *(const s16x8*)(yb + i * 1024);
        p1[i] = *(const s16x8*)(yb + i * 1024 + 512);
        m0[i] = bb0[i * 16];
        m1[i] = bb1[i * 16];
    }

    f32x4v accA0 = {0.f,0.f,0.f,0.f}, accB0 = {0.f,0.f,0.f,0.f};
    f32x4v accA1 = {0.f,0.f,0.f,0.f}, accB1 = {0.f,0.f,0.f,0.f};
#pragma unroll
    for (int wi = 0; wi < 16; ++wi) {
        const int slot = wi & 3;
        s16x8 b0 = p0[slot], b1 = p1[slot];
        u64 h0 = m0[slot], h1 = m1[slot];
        if (wi + 4 < 16) {
            p0[slot] = *(const s16x8*)(yb + (wi + 4) * 1024);
            p1[slot] = *(const s16x8*)(yb + (wi + 4) * 1024 + 512);
            m0[slot] = bb0[(wi + 4) * 16];
            m1[slot] = bb1[(wi + 4) * 16];
        }
        u64 ha = h0 >> (g * 8), hb = h1 >> (g * 8);
        accA0 = __builtin_amdgcn_mfma_f32_16x16x32_bf16(expand8((u32)ha & 0xFFu), b0, accA0, 0, 0, 0);
        accB0 = __builtin_amdgcn_mfma_f32_16x16x32_bf16(expand8(((u32)(ha >> 32)) & 0xFFu), b1, accB0, 0, 0, 0);
        accA1 = __builtin_amdgcn_mfma_f32_16x16x32_bf16(expand8((u32)hb & 0xFFu), b0, accA1, 0, 0, 0);
        accB1 = __builtin_amdgcn_mfma_f32_16x16x32_bf16(expand8(((u32)(hb >> 32)) & 0xFFu), b1, accB1, 0, 0, 0);
    }

    f32x4v acc0, acc1;
#pragma unroll
    for (int r = 0; r < 4; ++r) { acc0[r] = accA0[r] + accB0[r];
                                  acc1[r] = accA1[r] + accB1[r]; }

    const int s0a = row0 + 4 * g;
    const int s0b = row0 + 16 + 4 * g;
    const long yba = (long)b * YSWZ + ypos(n16, s0a);
    const long ybb = (long)b * YSWZ + ypos(n16, s0b);
    float y1a[4], y2a[4], y1b[4], y2b[4];
    if (LAST && ss == 0) {
#pragma unroll
        for (int r = 0; r < 4; ++r) {
            y1a[r] = bf16_f32(ysw1[yba + r * 1024]);
            y2a[r] = bf16_f32(ysw2[yba + r * 1024]);
            y1b[r] = bf16_f32(ysw1[ybb + r * 1024]);
            y2b[r] = bf16_f32(ysw2[ybb + r * 1024]);
        }
    }

    if (ss != 0) {
#pragma unroll
        for (int r = 0; r < 4; ++r) {
            red[0][ss - 1][r][lane] = acc0[r];
            red[1][ss - 1][r][lane] = acc1[r];
        }
    }
    __syncthreads();
    if (ss == 0) {
#pragma unroll
        for (int r = 0; r < 4; ++r) {
            acc0[r] += red[0][0][r][lane] + red[0][1][r][lane] + red[0][2][r][lane];
            acc1[r] += red[1][0][r][lane] + red[1][1][r][lane] + red[1][2][r][lane];
        }
        if (!LAST) {
#pragma unroll
            for (int r = 0; r < 4; ++r) {
                yout[yba + r * 1024] = (u16)bf16_rne(acc0[r]);
                yout[ybb + r * 1024] = (u16)bf16_rne(acc1[r]);
            }
        } else {
#pragma unroll
            for (int r = 0; r < 4; ++r) {
                t1[4 * g + r][n16]      = y1a[r];
                t2[4 * g + r][n16]      = y2a[r];
                t3[4 * g + r][n16]      = acc0[r];
                t1[16 + 4 * g + r][n16] = y1b[r];
                t2[16 + 4 * g + r][n16] = y2b[r];
                t3[16 + 4 * g + r][n16] = acc1[r];
            }
        }
    }

    if (LAST) {
        __syncthreads();
#pragma unroll
        for (int j = 0; j < 4; ++j) {
            int fi = tid + j * 256;
            int c = fi >> 7, row = (fi >> 2) & 31, k4 = fi & 3;
            const float4* kf = (const float4*)ker;
            float4 a = kf[(c * TT + 0) * 4 + k4];
            float4 d = kf[(c * TT + 1) * 4 + k4];
            float4 e = kf[(c * TT + 2) * 4 + k4];
            float4 e1, e2, e3;
            e1.x = a.x + d.x + e.x;               e1.y = a.y + d.y + e.y;
            e1.z = a.z + d.z + e.z;               e1.w = a.w + d.w + e.w;
            e2.x = a.x*d.x + a.x*e.x + d.x*e.x;   e2.y = a.y*d.y + a.y*e.y + d.y*e.y;
            e2.z = a.z*d.z + a.z*e.z + d.z*e.z;   e2.w = a.w*d.w + a.w*e.w + d.w*e.w;
            e3.x = a.x * d.x * e.x;               e3.y = a.y * d.y * e.y;
            e3.z = a.z * d.z * e.z;               e3.w = a.w * d.w * e.w;
            float4 y0 = *(const float4*)(labels + ((long)b * NN + row0 + row) * KK + k4 * 4);
            float4 v1 = *(const float4*)&t1[row][k4 * 4];
            float4 v2 = *(const float4*)&t2[row][k4 * 4];
            float4 v3 = *(const float4*)&t3[row][k4 * 4];
            float4 r;
            r.x = y0.x + e1.x * v1.x + e2.x * v2.x + e3.x * v3.x;
            r.y = y0.y + e1.y * v1.y + e2.y * v2.y + e3.y * v3.y;
            r.z = y0.z + e1.z * v1.z + e2.z * v2.z + e3.z * v3.z;
            r.w = y0.w + e1.w * v1.w + e2.w * v2.w + e3.w * v3.w;
            *(float4*)(out + (((long)b * CC + c) * NN + row0 + row) * KK + k4 * 4) = r;
        }
    }
}

// --------------------------------------------------------------- launch -----
extern "C" void kernel_launch(void* const* d_in, const int* in_sizes, int n_in,
                              void* d_out, int out_size, void* d_ws, size_t ws_size,
                              hipStream_t stream) {
    const float* labels = (const float*)d_in[0];   // [B,N,K] f32
    const int*   lig    = (const int*)d_in[1];     // [B,N,N] i32
    const float* ker    = (const float*)d_in[2];   // [C,T,K] f32
    float* out = (float*)d_out;

    u64* bits = (u64*)d_ws;                        // 8 MB
    u16* ysw0 = (u16*)((char*)d_ws + (long)BB * WPR * NN * 8);
    u16* ysw1 = ysw0 + (long)BB * YSWZ;
    u16* ysw2 = ysw1 + (long)BB * YSWZ;

    hipLaunchKernelGGL(pack_kernel, dim3(BB * 256 * 2), dim3(256), 0, stream,
                       lig, bits, labels, ysw0);

    dim3 sgrid(BB * (NN / 32));                    // 512 blocks
    hipLaunchKernelGGL((spmm2_k<false>), sgrid, dim3(256), 0, stream,
                       bits, ysw0, ysw1, (const u16*)nullptr,
                       (const u16*)nullptr, (const float*)nullptr,
                       (const float*)nullptr, (float*)nullptr);
    hipLaunchKernelGGL((spmm2_k<false>), sgrid, dim3(256), 0, stream,
                       bits, ysw1, ysw2, (const u16*)nullptr,
                       (const u16*)nullptr, (const float*)nullptr,
                       (const float*)nullptr, (float*)nullptr);
    hipLaunchKernelGGL((spmm2_k<true>),  sgrid, dim3(256), 0, stream,
                       bits, ysw2, (u16*)nullptr, ysw1, ysw2,
                       labels, ker, out);
}

// Round 21
// 74.536 us; speedup vs baseline: 2.1941x; 1.0140x over previous
//
#include <hip/hip_runtime.h>

// WL-conv factorized:  out[b,c,n,k] = Y0 + e1[c,k]*Y1 + e2[c,k]*Y2 + e3[c,k]*Y3
// with Ym = M^m labels and e_m the elementary symmetric polynomials of
// kernels[c,0..2,k] (per-step operators I + k_t∘M commute).
//
// 4 stream-ordered kernels:
//   pack: STANDALONE, now 4096 QUARTER-tile blocks (16 rows x 1024 cols,
//         64 KB each; 16 queued/CU, 4 resident) -> finer stall coverage and
//         tail balance than R20's 2048 half-tiles. Wave ss owns col-group
//         [256ss,256ss+256) of its quarter; depth-8 static pipeline.
//         Ballot->word mapping field-identical to R16/R20. Prep fused.
//   s1/s2/s3: R16-proven 32-row spmm (512 blocks, 2/CU), pipelines deepened
//         to DEPTH 8 (VGPR budget 256 at bounds(256,2); full unroll keeps
//         slots static per rule #20); s3 fuses combine + f4 epilogue.
// bits layout: bits[((b*256+rt)*64 + w)*16 + r]  (block-coalesced tiles)
// Y chained in ypos-permuted MFMA-B-fragment layout (coalesced 1KB B loads).
//
// d_out (8 MB): final output only.
// d_ws: bits 8MB | ysw0 | ysw1 | ysw2 (0.5 MB each, swizzled bf16).

#define BB 4
#define NN 4096
#define KK 16
#define CC 8
#define TT 3
#define WPR (NN / 64)
#define YSWZ (KK * NN)   // u16 elements per batch in swizzled Y (65536)

typedef unsigned long long u64;
typedef unsigned int u32;
typedef unsigned short u16;
typedef __attribute__((ext_vector_type(8))) short s16x8;
typedef __attribute__((ext_vector_type(4))) float f32x4v;

__device__ __forceinline__ u32 bf16_rne(float f) {
    u32 u = __float_as_uint(f);
    return (u + 0x7FFFu + ((u >> 16) & 1u)) >> 16;
}
__device__ __forceinline__ float bf16_f32(u32 h) {
    return __uint_as_float(h << 16);
}
__device__ __forceinline__ long ypos(int f, int s) {
    return ((long)(s >> 8) << 12) + (s & 3) * 1024 + ((s >> 7) & 1) * 512 +
           f * 32 + ((s >> 5) & 3) * 8 + ((s >> 2) & 7);
}

// byte (8 mask bits) -> 8 bf16 {0,1} packed in s16x8 (elem i = bit i)
__device__ __forceinline__ s16x8 expand8(u32 byt) {
    u32 n0 = byt & 0xFu, n1 = (byt >> 4) & 0xFu;
    u32 t0 = (n0 * 0x204081u) & 0x01010101u;
    u32 t1 = (n1 * 0x204081u) & 0x01010101u;
    u32 m0 = (t0 << 7) - t0;
    u32 m1 = (t1 << 7) - t1;
    union { u32 w[4]; s16x8 v; } u;
    u.w[0] = __builtin_amdgcn_perm(0u, m0, 0x0C010C00u) << 7;
    u.w[1] = __builtin_amdgcn_perm(0u, m0, 0x0C030C02u) << 7;
    u.w[2] = __builtin_amdgcn_perm(0u, m1, 0x0C010C00u) << 7;
    u.w[3] = __builtin_amdgcn_perm(0u, m1, 0x0C030C02u) << 7;
    return u.v;
}

// ---------------------------------------------------------------- pack ------
// grid = BB * 256 rt * 4 quarters = 4096 blocks of 256 threads (4 waves).
// Block (b, rt, h): rows [16rt,16rt+16) x cols [1024h, 1024h+1024).
// Wave ss: cols [256ss,+256) of the quarter; i = row 0..15, one int4/row;
// depth-8 pipeline, fully-static slots (full unroll).
// Word w = 16h + 4ss + c  <->  bit l = lig[row][256*(w>>2) + 4l + (w&3)]
// (identical to R16/R20's mapping). First 256 blocks also run prep.
__global__ __launch_bounds__(256, 4)
void pack_kernel(const int* __restrict__ lig, u64* __restrict__ bits,
                 const float* __restrict__ labels, u16* __restrict__ ysw0)
{
    __shared__ u64 bl[16][16];                   // [w_local][row] 2 KB
    const int bid = blockIdx.x;
    const int h   = bid & 3;
    const int rt  = (bid >> 2) & 255;
    const int b   = bid >> 10;
    const int tid = threadIdx.x;
    const int lane = tid & 63, ss = tid >> 6;
    const int row0 = rt * 16;

    // prep fused (first 256 blocks, one task per thread)
    int gid = bid * 256 + tid;
    if (gid < BB * KK * (NN / 4)) {              // 65536 tasks
        int s4 = (gid & (NN / 4 - 1)) * 4;
        int f  = (gid >> 10) & (KK - 1);
        int pb = gid >> 14;
        long base = (long)pb * YSWZ + ypos(f, s4);
        const float* lp = labels + ((long)pb * NN + s4) * KK + f;
#pragma unroll
        for (int j = 0; j < 4; ++j)
            ysw0[base + j * 1024] = (u16)bf16_rne(lp[j * KK]);
    }

    const int* lrow = lig + ((long)b * NN + row0) * NN + h * 1024 + ss * 256;
    auto laddr = [&](int i) {
        return (const int4*)(lrow + (long)i * NN + lane * 4);
    };
    int4 v[8];
#pragma unroll
    for (int i = 0; i < 8; ++i) v[i] = *laddr(i);
#pragma unroll
    for (int i = 0; i < 16; ++i) {
        const int slot = i & 7;                  // static under full unroll
        int4 cur = v[slot];
        if (i + 8 < 16) v[slot] = *laddr(i + 8);
        u64 m0 = __ballot(cur.x >= 1);
        u64 m1 = __ballot(cur.y >= 1);
        u64 m2 = __ballot(cur.z >= 1);
        u64 m3 = __ballot(cur.w >= 1);
        if (lane == 0) {
            const int wl = ss * 4;               // local word base
            bl[wl + 0][i] = m0; bl[wl + 1][i] = m1;
            bl[wl + 2][i] = m2; bl[wl + 3][i] = m3;
        }
    }
    __syncthreads();
    // coalesced 2 KB quarter-tile dump: words [16h, 16h+16)
    u64* dst = bits + (long)(b * 256 + rt) * 1024 + h * 256;
    dst[tid] = ((const u64*)bl)[tid];
}

// ------------------------------------------------- 32-row spmm --------------
// grid = BB*(NN/32) = 512 blocks of 256 threads, 2 blocks/CU (bounds 256,2).
// Two 16-row tiles (rt0, rt1) share every B-fragment load.
// DEPTH-8 rolling pipelines (VGPR budget 256; full unroll -> static slots).
template<bool LAST>
__global__ __launch_bounds__(256, 2)
void spmm2_k(const u64* __restrict__ bits, const u16* __restrict__ yin,
             u16* __restrict__ yout, const u16* __restrict__ ysw1,
             const u16* __restrict__ ysw2, const float* __restrict__ labels,
             const float* __restrict__ ker, float* __restrict__ out)
{
    __shared__ float red[2][3][4][64];                    // 6 KB
    __shared__ float t1[32][16], t2[32][16], t3[32][16];  // 6 KB (LAST)
    const int bid = blockIdx.x;
    const int rtp = bid & (NN / 32 - 1);
    const int b   = bid >> 7;
    const int tid = threadIdx.x;
    const int lane = tid & 63, ss = tid >> 6;
    const int n16 = lane & 15, g = lane >> 4;
    const int row0 = rtp * 32;
    const int rt0 = 2 * rtp, rt1 = 2 * rtp + 1;

    const u64* bb0 = bits + ((long)(b * (NN / 16) + rt0) * 64 + ss * 16) * 16 + n16;
    const u64* bb1 = bits + ((long)(b * (NN / 16) + rt1) * 64 + ss * 16) * 16 + n16;
    const u16* yb  = yin + (long)b * YSWZ + (ss * 16) * 1024 + n16 * 32 + g * 8;

    s16x8 p0[8], p1[8]; u64 m0[8], m1[8];
#pragma unroll
    for (int i = 0; i < 8; ++i) {
        p0[i] = *(const s16x8*)(yb + i * 1024);
        p1[i] = *(const s16x8*)(yb + i * 1024 + 512);
        m0[i] = bb0[i * 16];
        m1[i] = bb1[i * 16];
    }

    f32x4v accA0 = {0.f,0.f,0.f,0.f}, accB0 = {0.f,0.f,0.f,0.f};
    f32x4v accA1 = {0.f,0.f,0.f,0.f}, accB1 = {0.f,0.f,0.f,0.f};
#pragma unroll
    for (int wi = 0; wi < 16; ++wi) {
        const int slot = wi & 7;                 // static under full unroll
        s16x8 b0 = p0[slot], b1 = p1[slot];
        u64 h0 = m0[slot], h1 = m1[slot];
        if (wi + 8 < 16) {
            p0[slot] = *(const s16x8*)(yb + (wi + 8) * 1024);
            p1[slot] = *(const s16x8*)(yb + (wi + 8) * 1024 + 512);
            m0[slot] = bb0[(wi + 8) * 16];
            m1[slot] = bb1[(wi + 8) * 16];
        }
        u64 ha = h0 >> (g * 8), hb = h1 >> (g * 8);
        accA0 = __builtin_amdgcn_mfma_f32_16x16x32_bf16(expand8((u32)ha & 0xFFu), b0, accA0, 0, 0, 0);
        accB0 = __builtin_amdgcn_mfma_f32_16x16x32_bf16(expand8(((u32)(ha >> 32)) & 0xFFu), b1, accB0, 0, 0, 0);
        accA1 = __builtin_amdgcn_mfma_f32_16x16x32_bf16(expand8((u32)hb & 0xFFu), b0, accA1, 0, 0, 0);
        accB1 = __builtin_amdgcn_mfma_f32_16x16x32_bf16(expand8(((u32)(hb >> 32)) & 0xFFu), b1, accB1, 0, 0, 0);
    }

    f32x4v acc0, acc1;
#pragma unroll
    for (int r = 0; r < 4; ++r) { acc0[r] = accA0[r] + accB0[r];
                                  acc1[r] = accA1[r] + accB1[r]; }

    const int s0a = row0 + 4 * g;
    const int s0b = row0 + 16 + 4 * g;
    const long yba = (long)b * YSWZ + ypos(n16, s0a);
    const long ybb = (long)b * YSWZ + ypos(n16, s0b);
    float y1a[4], y2a[4], y1b[4], y2b[4];
    if (LAST && ss == 0) {
#pragma unroll
        for (int r = 0; r < 4; ++r) {
            y1a[r] = bf16_f32(ysw1[yba + r * 1024]);
            y2a[r] = bf16_f32(ysw2[yba + r * 1024]);
            y1b[r] = bf16_f32(ysw1[ybb + r * 1024]);
            y2b[r] = bf16_f32(ysw2[ybb + r * 1024]);
        }
    }

    if (ss != 0) {
#pragma unroll
        for (int r = 0; r < 4; ++r) {
            red[0][ss - 1][r][lane] = acc0[r];
            red[1][ss - 1][r][lane] = acc1[r];
        }
    }
    __syncthreads();
    if (ss == 0) {
#pragma unroll
        for (int r = 0; r < 4; ++r) {
            acc0[r] += red[0][0][r][lane] + red[0][1][r][lane] + red[0][2][r][lane];
            acc1[r] += red[1][0][r][lane] + red[1][1][r][lane] + red[1][2][r][lane];
        }
        if (!LAST) {
#pragma unroll
            for (int r = 0; r < 4; ++r) {
                yout[yba + r * 1024] = (u16)bf16_rne(acc0[r]);
                yout[ybb + r * 1024] = (u16)bf16_rne(acc1[r]);
            }
        } else {
#pragma unroll
            for (int r = 0; r < 4; ++r) {
                t1[4 * g + r][n16]      = y1a[r];
                t2[4 * g + r][n16]      = y2a[r];
                t3[4 * g + r][n16]      = acc0[r];
                t1[16 + 4 * g + r][n16] = y1b[r];
                t2[16 + 4 * g + r][n16] = y2b[r];
                t3[16 + 4 * g + r][n16] = acc1[r];
            }
        }
    }

    if (LAST) {
        __syncthreads();
#pragma unroll
        for (int j = 0; j < 4; ++j) {
            int fi = tid + j * 256;
            int c = fi >> 7, row = (fi >> 2) & 31, k4 = fi & 3;
            const float4* kf = (const float4*)ker;
            float4 a = kf[(c * TT + 0) * 4 + k4];
            float4 d = kf[(c * TT + 1) * 4 + k4];
            float4 e = kf[(c * TT + 2) * 4 + k4];
            float4 e1, e2, e3;
            e1.x = a.x + d.x + e.x;               e1.y = a.y + d.y + e.y;
            e1.z = a.z + d.z + e.z;               e1.w = a.w + d.w + e.w;
            e2.x = a.x*d.x + a.x*e.x + d.x*e.x;   e2.y = a.y*d.y + a.y*e.y + d.y*e.y;
            e2.z = a.z*d.z + a.z*e.z + d.z*e.z;   e2.w = a.w*d.w + a.w*e.w + d.w*e.w;
            e3.x = a.x * d.x * e.x;               e3.y = a.y * d.y * e.y;
            e3.z = a.z * d.z * e.z;               e3.w = a.w * d.w * e.w;
            float4 y0 = *(const float4*)(labels + ((long)b * NN + row0 + row) * KK + k4 * 4);
            float4 v1 = *(const float4*)&t1[row][k4 * 4];
            float4 v2 = *(const float4*)&t2[row][k4 * 4];
            float4 v3 = *(const float4*)&t3[row][k4 * 4];
            float4 r;
            r.x = y0.x + e1.x * v1.x + e2.x * v2.x + e3.x * v3.x;
            r.y = y0.y + e1.y * v1.y + e2.y * v2.y + e3.y * v3.y;
            r.z = y0.z + e1.z * v1.z + e2.z * v2.z + e3.z * v3.z;
            r.w = y0.w + e1.w * v1.w + e2.w * v2.w + e3.w * v3.w;
            *(float4*)(out + (((long)b * CC + c) * NN + row0 + row) * KK + k4 * 4) = r;
        }
    }
}

// --------------------------------------------------------------- launch -----
extern "C" void kernel_launch(void* const* d_in, const int* in_sizes, int n_in,
                              void* d_out, int out_size, void* d_ws, size_t ws_size,
                              hipStream_t stream) {
    const float* labels = (const float*)d_in[0];   // [B,N,K] f32
    const int*   lig    = (const int*)d_in[1];     // [B,N,N] i32
    const float* ker    = (const float*)d_in[2];   // [C,T,K] f32
    float* out = (float*)d_out;

    u64* bits = (u64*)d_ws;                        // 8 MB
    u16* ysw0 = (u16*)((char*)d_ws + (long)BB * WPR * NN * 8);
    u16* ysw1 = ysw0 + (long)BB * YSWZ;
    u16* ysw2 = ysw1 + (long)BB * YSWZ;

    hipLaunchKernelGGL(pack_kernel, dim3(BB * 256 * 4), dim3(256), 0, stream,
                       lig, bits, labels, ysw0);

    dim3 sgrid(BB * (NN / 32));                    // 512 blocks
    hipLaunchKernelGGL((spmm2_k<false>), sgrid, dim3(256), 0, stream,
                       bits, ysw0, ysw1, (const u16*)nullptr,
                       (const u16*)nullptr, (const float*)nullptr,
                       (const float*)nullptr, (float*)nullptr);
    hipLaunchKernelGGL((spmm2_k<false>), sgrid, dim3(256), 0, stream,
                       bits, ysw1, ysw2, (const u16*)nullptr,
                       (const u16*)nullptr, (const float*)nullptr,
                       (const float*)nullptr, (float*)nullptr);
    hipLaunchKernelGGL((spmm2_k<true>),  sgrid, dim3(256), 0, stream,
                       bits, ysw2, (u16*)nullptr, ysw1, ysw2,
                       labels, ker, out);
}

// Round 22
// 73.952 us; speedup vs baseline: 2.2115x; 1.0079x over previous
//
#include <hip/hip_runtime.h>

// WL-conv factorized:  out[b,c,n,k] = Y0 + e1[c,k]*Y1 + e2[c,k]*Y2 + e3[c,k]*Y3
// with Ym = M^m labels and e_m the elementary symmetric polynomials of
// kernels[c,0..2,k] (per-step operators I + k_t∘M commute).
//
// 4 stream-ordered kernels:
//   pack: 4096 quarter-tile blocks (16 rows x 1024 cols, 64 KB each), NOW
//         __launch_bounds__(256,8): depth-4 pipeline (16 VGPR) fits the
//         64-VGPR/8-waves-per-SIMD budget -> 8 resident blocks/CU = 32
//         waves/CU (R21 had 16). Doubled TLP halves every exposed-latency
//         window of the 256 MB stream. Slots static (full unroll, rule #20).
//   s1/s2/s3: R21-proven 32-row spmm, byte-identical (512 blocks, 2/CU,
//         depth-8 rolling pipelines; s3 fuses combine + f4 epilogue).
// bits layout: bits[((b*256+rt)*64 + w)*16 + r]  (block-coalesced tiles)
// Y chained in ypos-permuted MFMA-B-fragment layout (coalesced 1KB B loads).
//
// d_out (8 MB): final output only.
// d_ws: bits 8MB | ysw0 | ysw1 | ysw2 (0.5 MB each, swizzled bf16).

#define BB 4
#define NN 4096
#define KK 16
#define CC 8
#define TT 3
#define WPR (NN / 64)
#define YSWZ (KK * NN)   // u16 elements per batch in swizzled Y (65536)

typedef unsigned long long u64;
typedef unsigned int u32;
typedef unsigned short u16;
typedef __attribute__((ext_vector_type(8))) short s16x8;
typedef __attribute__((ext_vector_type(4))) float f32x4v;

__device__ __forceinline__ u32 bf16_rne(float f) {
    u32 u = __float_as_uint(f);
    return (u + 0x7FFFu + ((u >> 16) & 1u)) >> 16;
}
__device__ __forceinline__ float bf16_f32(u32 h) {
    return __uint_as_float(h << 16);
}
__device__ __forceinline__ long ypos(int f, int s) {
    return ((long)(s >> 8) << 12) + (s & 3) * 1024 + ((s >> 7) & 1) * 512 +
           f * 32 + ((s >> 5) & 3) * 8 + ((s >> 2) & 7);
}

// byte (8 mask bits) -> 8 bf16 {0,1} packed in s16x8 (elem i = bit i)
__device__ __forceinline__ s16x8 expand8(u32 byt) {
    u32 n0 = byt & 0xFu, n1 = (byt >> 4) & 0xFu;
    u32 t0 = (n0 * 0x204081u) & 0x01010101u;
    u32 t1 = (n1 * 0x204081u) & 0x01010101u;
    u32 m0 = (t0 << 7) - t0;
    u32 m1 = (t1 << 7) - t1;
    union { u32 w[4]; s16x8 v; } u;
    u.w[0] = __builtin_amdgcn_perm(0u, m0, 0x0C010C00u) << 7;
    u.w[1] = __builtin_amdgcn_perm(0u, m0, 0x0C030C02u) << 7;
    u.w[2] = __builtin_amdgcn_perm(0u, m1, 0x0C010C00u) << 7;
    u.w[3] = __builtin_amdgcn_perm(0u, m1, 0x0C030C02u) << 7;
    return u.v;
}

// ---------------------------------------------------------------- pack ------
// grid = BB * 256 rt * 4 quarters = 4096 blocks of 256 threads (4 waves).
// Block (b, rt, h): rows [16rt,16rt+16) x cols [1024h, 1024h+1024).
// Wave ss: cols [256ss,+256); i = row 0..15, one int4/row; depth-4 static
// pipeline. 8 blocks/CU resident (bounds(256,8), <=64 VGPR).
// Word w = 16h + 4ss + c  <->  bit l = lig[row][256*(w>>2) + 4l + (w&3)].
// First 256 blocks also run prep (labels -> swizzled bf16 Y0).
__global__ __launch_bounds__(256, 8)
void pack_kernel(const int* __restrict__ lig, u64* __restrict__ bits,
                 const float* __restrict__ labels, u16* __restrict__ ysw0)
{
    __shared__ u64 bl[16][16];                   // [w_local][row] 2 KB
    const int bid = blockIdx.x;
    const int h   = bid & 3;
    const int rt  = (bid >> 2) & 255;
    const int b   = bid >> 10;
    const int tid = threadIdx.x;
    const int lane = tid & 63, ss = tid >> 6;
    const int row0 = rt * 16;

    // prep fused (first 256 blocks, one task per thread)
    int gid = bid * 256 + tid;
    if (gid < BB * KK * (NN / 4)) {              // 65536 tasks
        int s4 = (gid & (NN / 4 - 1)) * 4;
        int f  = (gid >> 10) & (KK - 1);
        int pb = gid >> 14;
        long base = (long)pb * YSWZ + ypos(f, s4);
        const float* lp = labels + ((long)pb * NN + s4) * KK + f;
#pragma unroll
        for (int j = 0; j < 4; ++j)
            ysw0[base + j * 1024] = (u16)bf16_rne(lp[j * KK]);
    }

    const int* lrow = lig + ((long)b * NN + row0) * NN + h * 1024 + ss * 256;
    auto laddr = [&](int i) {
        return (const int4*)(lrow + (long)i * NN + lane * 4);
    };
    int4 v[4];
#pragma unroll
    for (int i = 0; i < 4; ++i) v[i] = *laddr(i);
#pragma unroll
    for (int i = 0; i < 16; ++i) {
        const int slot = i & 3;                  // static under full unroll
        int4 cur = v[slot];
        if (i + 4 < 16) v[slot] = *laddr(i + 4);
        u64 m0 = __ballot(cur.x >= 1);
        u64 m1 = __ballot(cur.y >= 1);
        u64 m2 = __ballot(cur.z >= 1);
        u64 m3 = __ballot(cur.w >= 1);
        if (lane == 0) {
            const int wl = ss * 4;               // local word base
            bl[wl + 0][i] = m0; bl[wl + 1][i] = m1;
            bl[wl + 2][i] = m2; bl[wl + 3][i] = m3;
        }
    }
    __syncthreads();
    // coalesced 2 KB quarter-tile dump: words [16h, 16h+16)
    u64* dst = bits + (long)(b * 256 + rt) * 1024 + h * 256;
    dst[tid] = ((const u64*)bl)[tid];
}

// ------------------------------------------------- 32-row spmm [R21] --------
// grid = BB*(NN/32) = 512 blocks of 256 threads, 2 blocks/CU (bounds 256,2).
// Two 16-row tiles (rt0, rt1) share every B-fragment load.
// DEPTH-8 rolling pipelines (VGPR budget 256; full unroll -> static slots).
template<bool LAST>
__global__ __launch_bounds__(256, 2)
void spmm2_k(const u64* __restrict__ bits, const u16* __restrict__ yin,
             u16* __restrict__ yout, const u16* __restrict__ ysw1,
             const u16* __restrict__ ysw2, const float* __restrict__ labels,
             const float* __restrict__ ker, float* __restrict__ out)
{
    __shared__ float red[2][3][4][64];                    // 6 KB
    __shared__ float t1[32][16], t2[32][16], t3[32][16];  // 6 KB (LAST)
    const int bid = blockIdx.x;
    const int rtp = bid & (NN / 32 - 1);
    const int b   = bid >> 7;
    const int tid = threadIdx.x;
    const int lane = tid & 63, ss = tid >> 6;
    const int n16 = lane & 15, g = lane >> 4;
    const int row0 = rtp * 32;
    const int rt0 = 2 * rtp, rt1 = 2 * rtp + 1;

    const u64* bb0 = bits + ((long)(b * (NN / 16) + rt0) * 64 + ss * 16) * 16 + n16;
    const u64* bb1 = bits + ((long)(b * (NN / 16) + rt1) * 64 + ss * 16) * 16 + n16;
    const u16* yb  = yin + (long)b * YSWZ + (ss * 16) * 1024 + n16 * 32 + g * 8;

    s16x8 p0[8], p1[8]; u64 m0[8], m1[8];
#pragma unroll
    for (int i = 0; i < 8; ++i) {
        p0[i] = *(const s16x8*)(yb + i * 1024);
        p1[i] = *(const s16x8*)(yb + i * 1024 + 512);
        m0[i] = bb0[i * 16];
        m1[i] = bb1[i * 16];
    }

    f32x4v accA0 = {0.f,0.f,0.f,0.f}, accB0 = {0.f,0.f,0.f,0.f};
    f32x4v accA1 = {0.f,0.f,0.f,0.f}, accB1 = {0.f,0.f,0.f,0.f};
#pragma unroll
    for (int wi = 0; wi < 16; ++wi) {
        const int slot = wi & 7;                 // static under full unroll
        s16x8 b0 = p0[slot], b1 = p1[slot];
        u64 h0 = m0[slot], h1 = m1[slot];
        if (wi + 8 < 16) {
            p0[slot] = *(const s16x8*)(yb + (wi + 8) * 1024);
            p1[slot] = *(const s16x8*)(yb + (wi + 8) * 1024 + 512);
            m0[slot] = bb0[(wi + 8) * 16];
            m1[slot] = bb1[(wi + 8) * 16];
        }
        u64 ha = h0 >> (g * 8), hb = h1 >> (g * 8);
        accA0 = __builtin_amdgcn_mfma_f32_16x16x32_bf16(expand8((u32)ha & 0xFFu), b0, accA0, 0, 0, 0);
        accB0 = __builtin_amdgcn_mfma_f32_16x16x32_bf16(expand8(((u32)(ha >> 32)) & 0xFFu), b1, accB0, 0, 0, 0);
        accA1 = __builtin_amdgcn_mfma_f32_16x16x32_bf16(expand8((u32)hb & 0xFFu), b0, accA1, 0, 0, 0);
        accB1 = __builtin_amdgcn_mfma_f32_16x16x32_bf16(expand8(((u32)(hb >> 32)) & 0xFFu), b1, accB1, 0, 0, 0);
    }

    f32x4v acc0, acc1;
#pragma unroll
    for (int r = 0; r < 4; ++r) { acc0[r] = accA0[r] + accB0[r];
                                  acc1[r] = accA1[r] + accB1[r]; }

    const int s0a = row0 + 4 * g;
    const int s0b = row0 + 16 + 4 * g;
    const long yba = (long)b * YSWZ + ypos(n16, s0a);
    const long ybb = (long)b * YSWZ + ypos(n16, s0b);
    float y1a[4], y2a[4], y1b[4], y2b[4];
    if (LAST && ss == 0) {
#pragma unroll
        for (int r = 0; r < 4; ++r) {
            y1a[r] = bf16_f32(ysw1[yba + r * 1024]);
            y2a[r] = bf16_f32(ysw2[yba + r * 1024]);
            y1b[r] = bf16_f32(ysw1[ybb + r * 1024]);
            y2b[r] = bf16_f32(ysw2[ybb + r * 1024]);
        }
    }

    if (ss != 0) {
#pragma unroll
        for (int r = 0; r < 4; ++r) {
            red[0][ss - 1][r][lane] = acc0[r];
            red[1][ss - 1][r][lane] = acc1[r];
        }
    }
    __syncthreads();
    if (ss == 0) {
#pragma unroll
        for (int r = 0; r < 4; ++r) {
            acc0[r] += red[0][0][r][lane] + red[0][1][r][lane] + red[0][2][r][lane];
            acc1[r] += red[1][0][r][lane] + red[1][1][r][lane] + red[1][2][r][lane];
        }
        if (!LAST) {
#pragma unroll
            for (int r = 0; r < 4; ++r) {
                yout[yba + r * 1024] = (u16)bf16_rne(acc0[r]);
                yout[ybb + r * 1024] = (u16)bf16_rne(acc1[r]);
            }
        } else {
#pragma unroll
            for (int r = 0; r < 4; ++r) {
                t1[4 * g + r][n16]      = y1a[r];
                t2[4 * g + r][n16]      = y2a[r];
                t3[4 * g + r][n16]      = acc0[r];
                t1[16 + 4 * g + r][n16] = y1b[r];
                t2[16 + 4 * g + r][n16] = y2b[r];
                t3[16 + 4 * g + r][n16] = acc1[r];
            }
        }
    }

    if (LAST) {
        __syncthreads();
#pragma unroll
        for (int j = 0; j < 4; ++j) {
            int fi = tid + j * 256;
            int c = fi >> 7, row = (fi >> 2) & 31, k4 = fi & 3;
            const float4* kf = (const float4*)ker;
            float4 a = kf[(c * TT + 0) * 4 + k4];
            float4 d = kf[(c * TT + 1) * 4 + k4];
            float4 e = kf[(c * TT + 2) * 4 + k4];
            float4 e1, e2, e3;
            e1.x = a.x + d.x + e.x;               e1.y = a.y + d.y + e.y;
            e1.z = a.z + d.z + e.z;               e1.w = a.w + d.w + e.w;
            e2.x = a.x*d.x + a.x*e.x + d.x*e.x;   e2.y = a.y*d.y + a.y*e.y + d.y*e.y;
            e2.z = a.z*d.z + a.z*e.z + d.z*e.z;   e2.w = a.w*d.w + a.w*e.w + d.w*e.w;
            e3.x = a.x * d.x * e.x;               e3.y = a.y * d.y * e.y;
            e3.z = a.z * d.z * e.z;               e3.w = a.w * d.w * e.w;
            float4 y0 = *(const float4*)(labels + ((long)b * NN + row0 + row) * KK + k4 * 4);
            float4 v1 = *(const float4*)&t1[row][k4 * 4];
            float4 v2 = *(const float4*)&t2[row][k4 * 4];
            float4 v3 = *(const float4*)&t3[row][k4 * 4];
            float4 r;
            r.x = y0.x + e1.x * v1.x + e2.x * v2.x + e3.x * v3.x;
            r.y = y0.y + e1.y * v1.y + e2.y * v2.y + e3.y * v3.y;
            r.z = y0.z + e1.z * v1.z + e2.z * v2.z + e3.z * v3.z;
            r.w = y0.w + e1.w * v1.w + e2.w * v2.w + e3.w * v3.w;
            *(float4*)(out + (((long)b * CC + c) * NN + row0 + row) * KK + k4 * 4) = r;
        }
    }
}

// --------------------------------------------------------------- launch -----
extern "C" void kernel_launch(void* const* d_in, const int* in_sizes, int n_in,
                              void* d_out, int out_size, void* d_ws, size_t ws_size,
                              hipStream_t stream) {
    const float* labels = (const float*)d_in[0];   // [B,N,K] f32
    const int*   lig    = (const int*)d_in[1];     // [B,N,N] i32
    const float* ker    = (const float*)d_in[2];   // [C,T,K] f32
    float* out = (float*)d_out;

    u64* bits = (u64*)d_ws;                        // 8 MB
    u16* ysw0 = (u16*)((char*)d_ws + (long)BB * WPR * NN * 8);
    u16* ysw1 = ysw0 + (long)BB * YSWZ;
    u16* ysw2 = ysw1 + (long)BB * YSWZ;

    hipLaunchKernelGGL(pack_kernel, dim3(BB * 256 * 4), dim3(256), 0, stream,
                       lig, bits, labels, ysw0);

    dim3 sgrid(BB * (NN / 32));                    // 512 blocks
    hipLaunchKernelGGL((spmm2_k<false>), sgrid, dim3(256), 0, stream,
                       bits, ysw0, ysw1, (const u16*)nullptr,
                       (const u16*)nullptr, (const float*)nullptr,
                       (const float*)nullptr, (float*)nullptr);
    hipLaunchKernelGGL((spmm2_k<false>), sgrid, dim3(256), 0, stream,
                       bits, ysw1, ysw2, (const u16*)nullptr,
                       (const u16*)nullptr, (const float*)nullptr,
                       (const float*)nullptr, (float*)nullptr);
    hipLaunchKernelGGL((spmm2_k<true>),  sgrid, dim3(256), 0, stream,
                       bits, ysw2, (u16*)nullptr, ysw1, ysw2,
                       labels, ker, out);
}